// Round 5
// baseline (1564.120 us; speedup 1.0000x reference)
//
#include <hip/hip_runtime.h>

#define HH 192
#define WW 192
#define PW 194
#define HWSZ (HH*WW)        // 36864
#define PHW (PW*PW)         // 37636
#define CHW (64*HWSZ)       // 2359296 per frame

typedef __attribute__((ext_vector_type(8))) short bf16x8;
typedef __attribute__((ext_vector_type(4))) short bf16x4;
typedef __attribute__((ext_vector_type(4))) float f32x4;
typedef __attribute__((ext_vector_type(4))) unsigned int u32x4;

typedef __attribute__((address_space(3))) void as3_void;
typedef __attribute__((address_space(1))) const void as1_cvoid;

__device__ __forceinline__ float bf2f(short h) {
    union { unsigned u; float f; } c; c.u = ((unsigned)(unsigned short)h) << 16; return c.f;
}
__device__ __forceinline__ short f2bf(float f) {
    union { float f; unsigned u; } c; c.f = f;
    unsigned u = c.u;
    return (short)((u + 0x7FFFu + ((u >> 16) & 1u)) >> 16);
}
__device__ __forceinline__ float sigm(float v) {
    return 1.f / (1.f + __expf(-v));
}

// ---------------------------------------------------------------------------
// Weight staging: phys layout (from wtxk) is [kb][9][COUT][8 slots][8] bf16
// with slot_phys = slot_log ^ (cout & 7) (bank swizzle pre-baked -> staging is
// a LINEAR copy via global_load_lds; ds_read applies the XOR; both-sides rule).
// One 64-cout tile per kb = 9*64*64 shorts = 73,728 B.
// ---------------------------------------------------------------------------
template<int COUT, int TPB>
__device__ __forceinline__ void stagew(short* lds, const short* wt, int kb, int mt,
                                       int tid, int wv)
{
    const short* wbase = wt + ((size_t)(kb*9)*COUT + mt*64)*64;
#pragma unroll
    for (int i = 0; i < 4608/TPB; ++i) {
        int q = i*TPB + tid;                    // granule 0..4607 (16B each)
        const short* gp = wbase + (size_t)(q >> 9)*COUT*64 + (q & 511)*8;
        __builtin_amdgcn_global_load_lds((as1_cvoid*)gp,
            (as3_void*)(lds + (i*TPB + wv*64)*8), 16, 0, 0);
    }
}

// ---------------------------------------------------------------------------
// Implicit-GEMM 3x3 SAME conv, weights in LDS, B-fragments direct from
// padded-NHWC bf16 global (L2-banded via XCD swizzle).
// TPB=256: block = 1 row x 64 couts; grid = nmt*HH, XCD band = 24 rows,
//          j ordered y-minor within mt so concurrent blocks share weights.
// TPB=512: block = 2 rows x 64 couts (waves 0-3 row0, 4-7 row1); grid = nmt*96.
// ---------------------------------------------------------------------------
template<int KB, int COUT, int TPB>
__global__ __launch_bounds__(TPB, 2)
void convk(const short* __restrict__ in0, int cs0, int cb0,
           const short* __restrict__ in1, int cs1, int cb1,
           const short* __restrict__ wt, const float* __restrict__ bias,
           short* __restrict__ outb, int pado, int rowW, int cdst, int lrelu)
{
    __shared__ __align__(16) short lds[9*64*64];   // 73,728 B
    const int tid = threadIdx.x;
    const int l  = tid & 63, wv = tid >> 6;
    const int lr = l & 15,  lg = l >> 4;
    const int band = blockIdx.x & 7;
    const int j    = blockIdx.x >> 3;
    int mt, y, x0;
    if constexpr (TPB == 512) {
        mt = j / 12;
        int yp = band*12 + (j - mt*12);
        y = yp*2 + (wv >> 2);
        x0 = (wv & 3)*48;
    } else {
        mt = j / 24;
        y = band*24 + (j - mt*24);
        x0 = wv*48;
    }

    f32x4 acc[4][3];
#pragma unroll
    for (int a = 0; a < 4; ++a)
#pragma unroll
        for (int b = 0; b < 3; ++b) acc[a][b] = f32x4{0.f,0.f,0.f,0.f};

#pragma unroll 1
    for (int kb = 0; kb < KB; ++kb) {
        const short* src = (kb == 0) ? in0 : in1;
        const int cs = (kb == 0) ? cs0 : cs1;
        const int cb = (kb == 0) ? cb0 : cb1;
        if (kb) __syncthreads();
        stagew<COUT, TPB>(lds, wt, kb, mt, tid, wv);
        __syncthreads();
#pragma unroll
        for (int dy = 0; dy < 3; ++dy)
#pragma unroll
        for (int dx = 0; dx < 3; ++dx) {
            const int tap = dy*3 + dx;
#pragma unroll
            for (int ks = 0; ks < 2; ++ks) {
                bf16x8 bv[3];
#pragma unroll
                for (int nf = 0; nf < 3; ++nf) {
                    int px = x0 + nf*16 + lr + dx;
                    bv[nf] = *reinterpret_cast<const bf16x8*>(
                        src + (size_t)((y+dy)*PW + px)*cs + cb + ks*32 + lg*8);
                }
                const int s = ks*4 + lg;
#pragma unroll
                for (int mf = 0; mf < 4; ++mf) {
                    int row = mf*16 + lr;
                    bf16x8 av = *reinterpret_cast<const bf16x8*>(
                        &lds[(tap*64 + row)*64 + ((s ^ (row & 7))*8)]);
                    acc[mf][0] = __builtin_amdgcn_mfma_f32_16x16x32_bf16(av, bv[0], acc[mf][0], 0,0,0);
                    acc[mf][1] = __builtin_amdgcn_mfma_f32_16x16x32_bf16(av, bv[1], acc[mf][1], 0,0,0);
                    acc[mf][2] = __builtin_amdgcn_mfma_f32_16x16x32_bf16(av, bv[2], acc[mf][2], 0,0,0);
                }
            }
        }
    }

    // epilogue: D row(cout) = lg*4 + j (+mf*16+mt*64), col(pixel) = lr
#pragma unroll
    for (int mf = 0; mf < 4; ++mf) {
        const int coutb = mt*64 + mf*16 + lg*4;
        f32x4 bv = *reinterpret_cast<const f32x4*>(bias + coutb);
#pragma unroll
        for (int nf = 0; nf < 3; ++nf) {
            const int x = x0 + nf*16 + lr;
            bf16x4 pk;
#pragma unroll
            for (int j2 = 0; j2 < 4; ++j2) {
                float t = acc[mf][nf][j2] + bv[j2];
                if (lrelu) t = (t >= 0.f) ? t : 0.1f*t;
                pk[j2] = f2bf(t);
            }
            *reinterpret_cast<bf16x4*>(outb + (size_t)((y+pado)*rowW + (x+pado))*cdst + coutb) = pk;
        }
    }
}

// ---------------------------------------------------------------------------
// Fused dual-gate kernel: r = p1*sig(conv(p1,w_c2)+b2) + p2*sig(conv(p2,w_c3)+b3)
// p1/p2 = halves of fusion (cs=128). Writes d_out frame (NCHW f32) + fpstate
// (padded NHWC bf16). wg = [2][9][64][64] phys-swizzled (wtc2, wtc3).
// ---------------------------------------------------------------------------
__global__ __launch_bounds__(256, 2)
void gatek(const short* __restrict__ fus, const short* __restrict__ wg,
           const float* __restrict__ b2, const float* __restrict__ b3,
           float* __restrict__ dml, short* __restrict__ fpst)
{
    __shared__ __align__(16) short lds[9*64*64];
    const int tid = threadIdx.x;
    const int l  = tid & 63, wv = tid >> 6;
    const int lr = l & 15,  lg = l >> 4;
    const int y  = (blockIdx.x & 7)*24 + (blockIdx.x >> 3);

    f32x4 acc1[4][3], acc2[4][3];
#pragma unroll
    for (int a = 0; a < 4; ++a)
#pragma unroll
        for (int b = 0; b < 3; ++b) { acc1[a][b] = f32x4{0.f,0.f,0.f,0.f}; acc2[a][b] = f32x4{0.f,0.f,0.f,0.f}; }

#pragma unroll 1
    for (int g = 0; g < 2; ++g) {
        if (g) __syncthreads();
        stagew<64, 256>(lds, wg + (size_t)g*9*64*64, 0, 0, tid, wv);
        __syncthreads();
#pragma unroll
        for (int dy = 0; dy < 3; ++dy)
#pragma unroll
        for (int dx = 0; dx < 3; ++dx) {
            const int tap = dy*3 + dx;
#pragma unroll
            for (int ks = 0; ks < 2; ++ks) {
                bf16x8 bv[3];
#pragma unroll
                for (int nf = 0; nf < 3; ++nf) {
                    int px = wv*48 + nf*16 + lr + dx;
                    bv[nf] = *reinterpret_cast<const bf16x8*>(
                        fus + (size_t)((y+dy)*PW + px)*128 + g*64 + ks*32 + lg*8);
                }
                const int s = ks*4 + lg;
#pragma unroll
                for (int mf = 0; mf < 4; ++mf) {
                    int row = mf*16 + lr;
                    bf16x8 av = *reinterpret_cast<const bf16x8*>(
                        &lds[(tap*64 + row)*64 + ((s ^ (row & 7))*8)]);
                    f32x4* ac = g ? &acc2[mf][0] : &acc1[mf][0];
                    ac[0] = __builtin_amdgcn_mfma_f32_16x16x32_bf16(av, bv[0], ac[0], 0,0,0);
                    ac[1] = __builtin_amdgcn_mfma_f32_16x16x32_bf16(av, bv[1], ac[1], 0,0,0);
                    ac[2] = __builtin_amdgcn_mfma_f32_16x16x32_bf16(av, bv[2], ac[2], 0,0,0);
                }
            }
        }
    }

#pragma unroll
    for (int mf = 0; mf < 4; ++mf) {
        const int c = mf*16 + lg*4;
        f32x4 v2 = *reinterpret_cast<const f32x4*>(b2 + c);
        f32x4 v3 = *reinterpret_cast<const f32x4*>(b3 + c);
#pragma unroll
        for (int nf = 0; nf < 3; ++nf) {
            const int x = wv*48 + nf*16 + lr;
            bf16x4 p1 = *reinterpret_cast<const bf16x4*>(fus + (size_t)((y+1)*PW + (x+1))*128 + c);
            bf16x4 p2 = *reinterpret_cast<const bf16x4*>(fus + (size_t)((y+1)*PW + (x+1))*128 + 64 + c);
            bf16x4 pk;
#pragma unroll
            for (int j = 0; j < 4; ++j) {
                float r = bf2f(p1[j]) * sigm(acc1[mf][nf][j] + v2[j])
                        + bf2f(p2[j]) * sigm(acc2[mf][nf][j] + v3[j]);
                dml[(size_t)(c + j)*HWSZ + y*WW + x] = r;
                pk[j] = f2bf(r);
            }
            *reinterpret_cast<bf16x4*>(fpst + (size_t)((y+1)*PW + (x+1))*64 + c) = pk;
        }
    }
}

// ---------------------------------------------------------------------------
// Dynamic per-pixel 3x3 kernel conv: out[c,y,x] = sum_t kp[y,x,t*64+c]*fp[y+dy,x+dx,c]
// kp: unpadded NHWC [HW][576] bf16 (bias already added); fp/out: padded NHWC
// ---------------------------------------------------------------------------
__global__ __launch_bounds__(256)
void kconvk(const short* __restrict__ kp, const short* __restrict__ fp,
            short* __restrict__ outp)
{
    int t  = blockIdx.x*256 + threadIdx.x;
    int cg = t & 7, pix = t >> 3;
    int y = pix / WW, x = pix - y*WW;
    float acc[8];
#pragma unroll
    for (int e = 0; e < 8; ++e) acc[e] = 0.f;
    const short* kpp = kp + (size_t)pix*576 + cg*8;
#pragma unroll
    for (int tap = 0; tap < 9; ++tap) {
        int dy = tap / 3, dx = tap - dy*3;
        bf16x8 kv = *reinterpret_cast<const bf16x8*>(kpp + tap*64);
        bf16x8 fv = *reinterpret_cast<const bf16x8*>(fp + (size_t)((y+dy)*PW + (x+dx))*64 + cg*8);
#pragma unroll
        for (int e = 0; e < 8; ++e) acc[e] += bf2f(kv[e]) * bf2f(fv[e]);
    }
    bf16x8 o;
#pragma unroll
    for (int e = 0; e < 8; ++e) o[e] = f2bf(acc[e]);
    *reinterpret_cast<bf16x8*>(outp + (size_t)((y+1)*PW + (x+1))*64 + cg*8) = o;
}

// ---------------------------------------------------------------------------
// NCHW f32 frame -> padded NHWC bf16 (interior only; border pre-zeroed)
// ---------------------------------------------------------------------------
__global__ __launch_bounds__(64)
void tonhwck(const float* __restrict__ src, short* __restrict__ dst)
{
    int b = blockIdx.x;
    int y = b / 3, x = (b - y*3)*64 + threadIdx.x;
    unsigned pk[32];
#pragma unroll
    for (int c = 0; c < 64; ++c) {
        unsigned h = (unsigned)(unsigned short)f2bf(src[(size_t)c*HWSZ + y*WW + x]);
        if (c & 1) pk[c>>1] |= h << 16; else pk[c>>1] = h;
    }
    u32x4* d = reinterpret_cast<u32x4*>(dst + (size_t)((y+1)*PW + (x+1))*64);
#pragma unroll
    for (int q = 0; q < 8; ++q) d[q] = u32x4{pk[4*q], pk[4*q+1], pk[4*q+2], pk[4*q+3]};
}

// ---------------------------------------------------------------------------
// weight [COUT][CIN][3][3] f32 -> phys [kb][9][COUT][slot^(co&7)][8] bf16
// ---------------------------------------------------------------------------
__global__ void wtxk(const float* __restrict__ src, short* __restrict__ dst,
                     int cout_n, int cin_n)
{
    int i = blockIdx.x*256 + threadIdx.x;
    if (i >= cout_n*cin_n) return;
    int co = i / cin_n, ci = i - co*cin_n;
    int kb = ci >> 6, cl = ci & 63, s = cl >> 3, e = cl & 7;
    const float* sp = src + (size_t)i*9;
    size_t base = ((size_t)(kb*9)*cout_n + co)*64 + ((s ^ (co & 7))*8) + e;
#pragma unroll
    for (int t = 0; t < 9; ++t)
        dst[base + (size_t)t*cout_n*64] = f2bf(sp[t]);
}

extern "C" void kernel_launch(void* const* d_in, const int* in_sizes, int n_in,
                              void* d_out, int out_size, void* d_ws, size_t ws_size,
                              hipStream_t stream)
{
    const float* feature = (const float*)d_in[0];
    const float* w_kc1 = (const float*)d_in[1];
    const float* b_kc1 = (const float*)d_in[2];
    const float* w_kc2 = (const float*)d_in[3];
    const float* b_kc2 = (const float*)d_in[4];
    const float* w_c1  = (const float*)d_in[5];
    const float* b_c1  = (const float*)d_in[6];
    const float* w_c2  = (const float*)d_in[7];
    const float* b_c2  = (const float*)d_in[8];
    const float* w_c3  = (const float*)d_in[9];
    const float* b_c3  = (const float*)d_in[10];
    float* out = (float*)d_out;
    char* ws = (char*)d_ws;

    size_t off = 0;
    auto alloc = [&](size_t bytes) -> void* {
        void* p = ws + off; off += (bytes + 255) & ~(size_t)255; return p;
    };
    short* wt1   = (short*)alloc((size_t)2*9*64*64*2);    // conv1 (CIN=128,COUT=64)
    short* wt2   = (short*)alloc((size_t)9*576*64*2);     // kc2  (CIN=64, COUT=576)
    short* wtc1  = (short*)alloc((size_t)2*9*128*64*2);   // c1   (CIN=128,COUT=128)
    short* wg    = (short*)alloc((size_t)2*9*64*64*2);    // c2,c3 concatenated
    char*  zbase = ws + off;                  // contiguous zero-init block
    short* featX   = (short*)alloc((size_t)PHW*64*2);
    short* fpinit  = (short*)alloc((size_t)PHW*64*2);
    short* fpstate = (short*)alloc((size_t)PHW*64*2);
    short* t1      = (short*)alloc((size_t)PHW*64*2);
    short* fpmid   = (short*)alloc((size_t)PHW*64*2);
    short* fusion  = (short*)alloc((size_t)PHW*128*2);
    size_t zbytes = (size_t)((ws + off) - zbase);
    short* kp   = (short*)alloc((size_t)HWSZ*576*2);
    (void)ws_size; (void)in_sizes; (void)n_in; (void)out_size;

    hipMemsetAsync(zbase, 0, zbytes, stream);   // borders of padded buffers = 0
    wtxk<<<(64*128 + 255)/256, 256, 0, stream>>>(w_kc1, wt1, 64, 128);
    wtxk<<<(576*64 + 255)/256, 256, 0, stream>>>(w_kc2, wt2, 576, 64);
    wtxk<<<(128*128 + 255)/256, 256, 0, stream>>>(w_c1, wtc1, 128, 128);
    wtxk<<<(64*64 + 255)/256, 256, 0, stream>>>(w_c2, wg, 64, 64);
    wtxk<<<(64*64 + 255)/256, 256, 0, stream>>>(w_c3, wg + (size_t)9*64*64, 64, 64);
    tonhwck<<<576, 64, 0, stream>>>(feature + (size_t)9*CHW, fpinit);

    for (int i = 8; i >= 0; --i) {
        const short* fpin = (i == 8) ? fpinit : fpstate;
        tonhwck<<<576, 64, 0, stream>>>(feature + (size_t)i*CHW, featX);
        // t1 = lrelu(conv(concat(x, fp), w_kc1) + b)
        convk<2, 64, 256><<<HH, 256, 0, stream>>>(featX, 64, 0, fpin, 64, 0,
            wt1, b_kc1, t1, 1, PW, 64, 1);
        // kp = conv(t1, w_kc2) + b   [2 rows/block, 8 waves]
        convk<1, 576, 512><<<9*96, 512, 0, stream>>>(t1, 64, 0, nullptr, 0, 0,
            wt2, b_kc2, kp, 0, WW, 576, 0);
        // fpmid = kernel_conv(fp, kp)
        kconvk<<<1152, 256, 0, stream>>>(kp, fpin, fpmid);
        // fusion = lrelu(conv(concat(x, fpmid), w_c1) + b)
        convk<2, 128, 256><<<2*HH, 256, 0, stream>>>(featX, 64, 0, fpmid, 64, 0,
            wtc1, b_c1, fusion, 1, PW, 128, 1);
        // out[:,i] = fpstate = p1*sig(conv(p1,w_c2)+b2) + p2*sig(conv(p2,w_c3)+b3)
        gatek<<<HH, 256, 0, stream>>>(fusion, wg, b_c2, b_c3,
            out + (size_t)i*CHW, fpstate);
    }
    hipMemcpyAsync(out + (size_t)9*CHW, feature + (size_t)9*CHW,
                   (size_t)CHW*sizeof(float), hipMemcpyDeviceToDevice, stream);
}